// Round 6
// baseline (618.236 us; speedup 1.0000x reference)
//
#include <hip/hip_runtime.h>

#define B_  2
#define S_  2048
#define D_  2048
#define H_  16
#define HD_ 128

typedef __bf16 bf16;
typedef __bf16 bf16x4 __attribute__((ext_vector_type(4)));
typedef __bf16 bf16x8 __attribute__((ext_vector_type(8)));
typedef float  f32x4  __attribute__((ext_vector_type(4)));

// async global->LDS 16B copy: lds dst = wave-uniform base + lane*16
__device__ __forceinline__ void gld_lds16(const void* g, void* l) {
    __builtin_amdgcn_global_load_lds(
        (const __attribute__((address_space(1))) unsigned int*)g,
        (__attribute__((address_space(3))) unsigned int*)l, 16, 0, 0);
}

// ---------------- precast: x f32 -> hi/lo bf16 planes ----------------
__global__ __launch_bounds__(256)
void precast_kernel(const float* __restrict__ x, bf16* __restrict__ xh,
                    bf16* __restrict__ xl) {
    int i = (blockIdx.x * 256 + threadIdx.x) * 8;
    float4 a = *(const float4*)(x + i);
    float4 b = *(const float4*)(x + i + 4);
    float av[8] = {a.x, a.y, a.z, a.w, b.x, b.y, b.z, b.w};
    bf16x8 h8, l8;
#pragma unroll
    for (int e = 0; e < 8; e++) {
        bf16 hv = (bf16)av[e];
        h8[e] = hv;
        l8[e] = (bf16)(av[e] - (float)hv);
    }
    *(bf16x8*)(xh + i) = h8;
    *(bf16x8*)(xl + i) = l8;
}

// =================== GEMM: C[m,n] = sum_k A[m,k]*W[n,k] ===================
// A planes bf16 via global_load_lds + XOR column swizzle; B f32 VALU-staged.
// MODE 0: split A (xh,xl), sections q|k|v; epilogue *hm; q,k -> hi/lo planes
//         [bh][s][d]; v -> TRANSPOSED plane [bh][d][s] (for attn V^T staging).
// MODE 1: single A (attn_out); epilogue f32.
#define BK 64

template<int MODE>
__global__ __launch_bounds__(256, 3)
void gemm_nt(const bf16* __restrict__ Ah_g, const bf16* __restrict__ Al_g,
             const float* __restrict__ B0, const float* __restrict__ B1,
             const float* __restrict__ B2,
             const float* __restrict__ swp, const float* __restrict__ hm,
             bf16* __restrict__ qh_, bf16* __restrict__ ql_,
             bf16* __restrict__ kh_, bf16* __restrict__ kl_,
             bf16* __restrict__ vt_, float* __restrict__ Cf) {
    const int K = D_;
    __shared__ bf16 Ah[128 * 64];
    __shared__ bf16 Al[128 * 64];
    __shared__ bf16 Bs[128 * 64];
    const int t = threadIdx.x;
    const int wave = t >> 6, lane = t & 63;
    const int wr = wave >> 1, wc = wave & 1;
    const int m0 = blockIdx.y * 128, n0 = blockIdx.x * 128;
    const int lrow = lane & 15, lquad = lane >> 4;
    const float sw = swp[0];

    const int which = (MODE == 0) ? (n0 >> 11) : 0;
    const bool split = (MODE == 0) && (which < 2);

    const float* Bp;
    if (MODE == 0) {
        Bp = (which == 0) ? B0 : ((which == 1) ? B1 : B2);
        Bp += (size_t)(n0 & (D_ - 1)) * K;
    } else {
        Bp = B0 + (size_t)n0 * K;
    }

    const int srow8 = lane >> 3;
    const int sgrp  = lane & 7;
    const int g0 = (lquad)     ^ (lrow & 7);
    const int g1 = (lquad + 4) ^ (lrow & 7);

    f32x4 acc[4][4];
#pragma unroll
    for (int i = 0; i < 4; i++)
#pragma unroll
        for (int j = 0; j < 4; j++) acc[i][j] = (f32x4){0.f, 0.f, 0.f, 0.f};

    for (int k0 = 0; k0 < K; k0 += BK) {
#pragma unroll
        for (int p = 0; p < 4; p++) {
            int r = wave * 32 + p * 8 + srow8;
            int gcol = (sgrp ^ (r & 7)) * 8;
            gld_lds16(Ah_g + (size_t)(m0 + r) * K + k0 + gcol,
                      &Ah[(wave * 32 + p * 8) * 64]);
            if (split)
                gld_lds16(Al_g + (size_t)(m0 + r) * K + k0 + gcol,
                          &Al[(wave * 32 + p * 8) * 64]);
        }
#pragma unroll
        for (int p = 0; p < 4; p++) {
            int r = p * 32 + (t >> 3);
            int gcol = (sgrp ^ (r & 7)) * 8;
            const float* bp = Bp + (size_t)r * K + k0 + gcol;
            float4 blo = *(const float4*)bp;
            float4 bhi = *(const float4*)(bp + 4);
            bf16x8 b8;
            b8[0] = (bf16)(blo.x * sw); b8[1] = (bf16)(blo.y * sw);
            b8[2] = (bf16)(blo.z * sw); b8[3] = (bf16)(blo.w * sw);
            b8[4] = (bf16)(bhi.x * sw); b8[5] = (bf16)(bhi.y * sw);
            b8[6] = (bf16)(bhi.z * sw); b8[7] = (bf16)(bhi.w * sw);
            *(bf16x8*)&Bs[r * 64 + sgrp * 8] = b8;
        }
        __syncthreads();

#pragma unroll
        for (int kk = 0; kk < 2; kk++) {
            const int gA = kk ? g1 : g0;
            bf16x8 afh[4], afl[4], bfr[4];
#pragma unroll
            for (int i = 0; i < 4; i++) {
                int row = wr * 64 + i * 16 + lrow;
                afh[i] = *(const bf16x8*)&Ah[row * 64 + gA * 8];
                if (split) afl[i] = *(const bf16x8*)&Al[row * 64 + gA * 8];
            }
#pragma unroll
            for (int j = 0; j < 4; j++) {
                int row = wc * 64 + j * 16 + lrow;
                bfr[j] = *(const bf16x8*)&Bs[row * 64 + gA * 8];
            }
#pragma unroll
            for (int i = 0; i < 4; i++)
#pragma unroll
                for (int j = 0; j < 4; j++) {
                    acc[i][j] = __builtin_amdgcn_mfma_f32_16x16x32_bf16(
                        afh[i], bfr[j], acc[i][j], 0, 0, 0);
                    if (split)
                        acc[i][j] = __builtin_amdgcn_mfma_f32_16x16x32_bf16(
                            afl[i], bfr[j], acc[i][j], 0, 0, 0);
                }
        }
        __syncthreads();
    }

#pragma unroll
    for (int i = 0; i < 4; i++) {
#pragma unroll
        for (int j = 0; j < 4; j++) {
#pragma unroll
            for (int r = 0; r < 4; r++) {
                int m = m0 + wr * 64 + i * 16 + lquad * 4 + r;
                int n = n0 + wc * 64 + j * 16 + lrow;
                float v = acc[i][j][r];
                if (MODE == 0) {
                    int e = n & (D_ - 1);
                    int h = e >> 7, hd = e & (HD_ - 1);
                    int b = m >> 11, s = m & (S_ - 1);
                    v *= hm[h];
                    if (which == 2) {
                        // V transposed: [bh][d][s]
                        vt_[((size_t)(b * H_ + h) * HD_ + hd) * S_ + s] = (bf16)v;
                    } else {
                        size_t idx = (((size_t)b * H_ + h) * S_ + s) * HD_ + hd;
                        bf16 hv = (bf16)v;
                        bf16 lv = (bf16)(v - (float)hv);
                        if (which == 0) { qh_[idx] = hv; ql_[idx] = lv; }
                        else            { kh_[idx] = hv; kl_[idx] = lv; }
                    }
                } else {
                    Cf[(size_t)m * D_ + n] = v;
                }
            }
        }
    }
}

// =================== causal flash attention (MFMA, split QK) ===================
// 128 q rows/block; wave w owns rows [w*32, w*32+32) as two 16-row MFMA tiles
// (Q frags in registers, hi+lo). K chunks of 64 rows (hi/lo) + V^T staged via
// global_load_lds with XOR swizzle (no pad, no staging VALU). LDS 64 KiB ->
// 2 blocks/CU. Block pairing: qblk k with 15-k -> uniform 34 chunks per CU.
__global__ __launch_bounds__(256, 2)
void attn_kernel(const bf16* __restrict__ qh_, const bf16* __restrict__ ql_,
                 const bf16* __restrict__ kh_, const bf16* __restrict__ kl_,
                 const bf16* __restrict__ vt_, const float* __restrict__ am,
                 bf16* __restrict__ outp) {
    const int bh = blockIdx.x & 31;
    const int half = blockIdx.x >> 8;                 // 0: first 256 blocks
    const int qblk = half ? ((blockIdx.x - 256) >> 5) : (15 - (blockIdx.x >> 5));
    const int b = bh >> 4, h = bh & 15;
    const int i0 = qblk * 128;
    const int t = threadIdx.x, wave = t >> 6, lane = t & 63;
    const int lrow = lane & 15, quad = lane >> 4;

    __shared__ bf16 sh[32768];                        // 64 KiB
    bf16* skh = sh;                                   // [64][128] swizzled
    bf16* skl = sh + 8192;
    bf16* svt = sh + 16384;                           // [128][64] swizzled
    bf16* spp = sh + 24576 + wave * 2048;             // per-wave P [32][64]

    const size_t kbase = (size_t)bh * S_ * HD_;
    const size_t vbase = (size_t)bh * HD_ * S_;

    // Q fragments (hi+lo), two 16-row tiles, straight to registers
    bf16x8 qhf[2][4], qlf[2][4];
#pragma unroll
    for (int ib = 0; ib < 2; ib++) {
        int qrow = i0 + wave * 32 + ib * 16 + lrow;
#pragma unroll
        for (int c = 0; c < 4; c++) {
            qhf[ib][c] = *(const bf16x8*)&qh_[kbase + (size_t)qrow * HD_ + c * 32 + quad * 8];
            qlf[ib][c] = *(const bf16x8*)&ql_[kbase + (size_t)qrow * HD_ + c * 32 + quad * 8];
        }
    }

    float m_i[2][4], l_i[2][4];
    f32x4 O[2][8];
#pragma unroll
    for (int ib = 0; ib < 2; ib++) {
#pragma unroll
        for (int r = 0; r < 4; r++) { m_i[ib][r] = -INFINITY; l_i[ib][r] = 0.f; }
#pragma unroll
        for (int n2 = 0; n2 < 8; n2++) O[ib][n2] = (f32x4){0.f, 0.f, 0.f, 0.f};
    }

    const float scale = 0.08838834764831845f;  // 1/sqrt(128)
    const int iwmin = i0 + wave * 32;
    const int iwmax = iwmin + 31;

    for (int j0 = 0; j0 <= i0 + 64; j0 += 64) {
        __syncthreads();
        // stage K chunk (hi+lo): async, source-swizzled
#pragma unroll
        for (int p = 0; p < 4; p++) {
            int rb = wave * 16 + p * 4;
            int r = rb + (lane >> 4);
            int gl = ((lane & 15) ^ (r & 7)) * 8;
            gld_lds16(kh_ + kbase + (size_t)(j0 + r) * HD_ + gl, &skh[rb * 128]);
            gld_lds16(kl_ + kbase + (size_t)(j0 + r) * HD_ + gl, &skl[rb * 128]);
        }
        // stage V^T chunk: async, source-swizzled
#pragma unroll
        for (int p = 0; p < 4; p++) {
            int db = wave * 32 + p * 8;
            int d = db + (lane >> 3);
            int gl = ((lane & 7) ^ (d & 7)) * 8;
            gld_lds16(vt_ + vbase + (size_t)d * S_ + j0 + gl, &svt[db * 64]);
        }
        __syncthreads();

        if (j0 <= iwmax) {
            float amadd[4];
#pragma unroll
            for (int nt = 0; nt < 4; nt++)
                amadd[nt] = (1.0f - am[b * S_ + j0 + nt * 16 + lrow]) * -10000.0f;

            // QK^T: 2 i-tiles x 4 j-tiles, split 3-MFMA; B-frags shared across i
            f32x4 s4[2][4];
#pragma unroll
            for (int ib = 0; ib < 2; ib++)
#pragma unroll
                for (int nt = 0; nt < 4; nt++) s4[ib][nt] = (f32x4){0.f, 0.f, 0.f, 0.f};
#pragma unroll
            for (int c = 0; c < 4; c++) {
#pragma unroll
                for (int nt = 0; nt < 4; nt++) {
                    int ka = (nt * 16 + lrow) * 128 + (((c * 4 + quad) ^ (lrow & 7)) * 8);
                    bf16x8 kb8 = *(const bf16x8*)&skh[ka];
                    bf16x8 lb8 = *(const bf16x8*)&skl[ka];
#pragma unroll
                    for (int ib = 0; ib < 2; ib++) {
                        s4[ib][nt] = __builtin_amdgcn_mfma_f32_16x16x32_bf16(qhf[ib][c], kb8, s4[ib][nt], 0, 0, 0);
                        s4[ib][nt] = __builtin_amdgcn_mfma_f32_16x16x32_bf16(qhf[ib][c], lb8, s4[ib][nt], 0, 0, 0);
                        s4[ib][nt] = __builtin_amdgcn_mfma_f32_16x16x32_bf16(qlf[ib][c], kb8, s4[ib][nt], 0, 0, 0);
                    }
                }
            }

            const bool msk = (j0 + 63 >= iwmin);
#pragma unroll
            for (int ib = 0; ib < 2; ib++) {
#pragma unroll
                for (int r = 0; r < 4; r++) {
                    const int irow = iwmin + ib * 16 + quad * 4 + r;
                    float sv[4], pw[4];
                    float mx = -INFINITY;
#pragma unroll
                    for (int nt = 0; nt < 4; nt++) {
                        float xv = s4[ib][nt][r] * scale + amadd[nt];
                        if (msk && (j0 + nt * 16 + lrow) > irow) xv = -INFINITY;
                        sv[nt] = xv;
                        mx = fmaxf(mx, xv);
                    }
#pragma unroll
                    for (int off = 1; off < 16; off <<= 1) mx = fmaxf(mx, __shfl_xor(mx, off));
                    float mnew = fmaxf(m_i[ib][r], mx);
                    float alpha = __expf(m_i[ib][r] - mnew);
                    float ps = 0.f;
#pragma unroll
                    for (int nt = 0; nt < 4; nt++) { pw[nt] = __expf(sv[nt] - mnew); ps += pw[nt]; }
#pragma unroll
                    for (int off = 1; off < 16; off <<= 1) ps += __shfl_xor(ps, off);
                    l_i[ib][r] = l_i[ib][r] * alpha + ps;
                    m_i[ib][r] = mnew;
#pragma unroll
                    for (int n2 = 0; n2 < 8; n2++) O[ib][n2][r] *= alpha;
                    const int rl = ib * 16 + quad * 4 + r;
#pragma unroll
                    for (int nt = 0; nt < 4; nt++) {
                        int phys = (nt * 2 + (lrow >> 3)) ^ (rl & 7);
                        spp[rl * 64 + phys * 8 + (lrow & 7)] = (bf16)pw[nt];
                    }
                }
            }
            __asm__ volatile("s_waitcnt lgkmcnt(0)" ::: "memory");   // spp per-wave

            // PV: O += P * V (V^T frags shared across i-tiles)
#pragma unroll
            for (int k2 = 0; k2 < 2; k2++) {
                const int gp = ((quad + k2 * 4) ^ (lrow & 7)) * 8;
                bf16x8 pf0 = *(const bf16x8*)&spp[(lrow) * 64 + gp];
                bf16x8 pf1 = *(const bf16x8*)&spp[(16 + lrow) * 64 + gp];
#pragma unroll
                for (int n2 = 0; n2 < 8; n2++) {
                    bf16x8 vf8 = *(const bf16x8*)&svt[(n2 * 16 + lrow) * 64 + gp];
                    O[0][n2] = __builtin_amdgcn_mfma_f32_16x16x32_bf16(pf0, vf8, O[0][n2], 0, 0, 0);
                    O[1][n2] = __builtin_amdgcn_mfma_f32_16x16x32_bf16(pf1, vf8, O[1][n2], 0, 0, 0);
                }
            }
        }
    }

#pragma unroll
    for (int ib = 0; ib < 2; ib++) {
        float inv[4];
#pragma unroll
        for (int r = 0; r < 4; r++) inv[r] = 1.0f / l_i[ib][r];
#pragma unroll
        for (int n2 = 0; n2 < 8; n2++)
#pragma unroll
            for (int r = 0; r < 4; r++) {
                int srow = iwmin + ib * 16 + quad * 4 + r;
                outp[((size_t)(b * S_ + srow)) * D_ + h * HD_ + n2 * 16 + lrow] =
                    (bf16)(O[ib][n2][r] * inv[r]);
            }
    }
}

// =================== launch ===================
extern "C" void kernel_launch(void* const* d_in, const int* in_sizes, int n_in,
                              void* d_out, int out_size, void* d_ws, size_t ws_size,
                              hipStream_t stream) {
    const float* x  = (const float*)d_in[0];
    const float* qm = (const float*)d_in[1];
    const float* km = (const float*)d_in[2];
    const float* vm = (const float*)d_in[3];
    const float* om = (const float*)d_in[4];
    const float* hm = (const float*)d_in[5];
    const float* am = (const float*)d_in[6];
    const float* sw = (const float*)d_in[7];
    float* out = (float*)d_out;

    // ws (96 MiB): [xh | xl | qh | ql | kh | kl]; vt lives in d_out (free
    // until gemm1 overwrites it); attn_out overlays xh/xl after gemm0.
    const size_t P = (size_t)B_ * H_ * S_ * HD_ * sizeof(bf16);   // 16777216
    char* ws = (char*)d_ws;
    bf16* xh = (bf16*)(ws + 0 * P);
    bf16* xl = (bf16*)(ws + 1 * P);
    bf16* qh = (bf16*)(ws + 2 * P);
    bf16* ql = (bf16*)(ws + 3 * P);
    bf16* kh = (bf16*)(ws + 4 * P);
    bf16* kl = (bf16*)(ws + 5 * P);
    bf16* vt = (bf16*)d_out;                    // [bh][d][s], 16 MiB of d_out
    bf16* attn_out = (bf16*)(ws + 0 * P);

    precast_kernel<<<(B_ * S_ * D_) / (256 * 8), 256, 0, stream>>>(x, xh, xl);

    // QKV projection, split-precision q,k: M=4096, N=6144, K=2048
    gemm_nt<0><<<dim3(48, 32), 256, 0, stream>>>(
        xh, xl, qm, km, vm, sw, hm, qh, ql, kh, kl, vt, nullptr);

    // attention: 512 blocks (32 bh x 16 qblk), paired heavy+light per CU
    attn_kernel<<<512, 256, 0, stream>>>(qh, ql, kh, kl, vt, am, attn_out);

    // output projection: M=4096, N=2048, K=2048, f32 out
    gemm_nt<1><<<dim3(16, 32), 256, 0, stream>>>(
        attn_out, nullptr, om, nullptr, nullptr, sw, hm,
        nullptr, nullptr, nullptr, nullptr, nullptr, out);
}

// Round 7
// 493.655 us; speedup vs baseline: 1.2524x; 1.2524x over previous
//
#include <hip/hip_runtime.h>

#define B_  2
#define S_  2048
#define D_  2048
#define H_  16
#define HD_ 128

typedef __bf16 bf16;
typedef __bf16 bf16x4 __attribute__((ext_vector_type(4)));
typedef __bf16 bf16x8 __attribute__((ext_vector_type(8)));
typedef float  f32x4  __attribute__((ext_vector_type(4)));

// async global->LDS 16B copy: lds dst = wave-uniform base + lane*16
__device__ __forceinline__ void gld_lds16(const void* g, void* l) {
    __builtin_amdgcn_global_load_lds(
        (const __attribute__((address_space(1))) unsigned int*)g,
        (__attribute__((address_space(3))) unsigned int*)l, 16, 0, 0);
}

// ---------------- precast: x f32 -> hi/lo bf16 planes ----------------
__global__ __launch_bounds__(256)
void precast_kernel(const float* __restrict__ x, bf16* __restrict__ xh,
                    bf16* __restrict__ xl) {
    int i = (blockIdx.x * 256 + threadIdx.x) * 8;
    float4 a = *(const float4*)(x + i);
    float4 b = *(const float4*)(x + i + 4);
    float av[8] = {a.x, a.y, a.z, a.w, b.x, b.y, b.z, b.w};
    bf16x8 h8, l8;
#pragma unroll
    for (int e = 0; e < 8; e++) {
        bf16 hv = (bf16)av[e];
        h8[e] = hv;
        l8[e] = (bf16)(av[e] - (float)hv);
    }
    *(bf16x8*)(xh + i) = h8;
    *(bf16x8*)(xl + i) = l8;
}

// ---------------- V transpose: [bh][s][d] -> [bh][d][s], LDS-tiled ----------------
// grid: 32 bh x 32 s-tiles; tile = 64 s x 128 d.
__global__ __launch_bounds__(256)
void transpose_v(const bf16* __restrict__ vp, bf16* __restrict__ vt) {
    const int bh = blockIdx.x >> 5;
    const int s0 = (blockIdx.x & 31) * 64;
    const int t = threadIdx.x;
    __shared__ bf16 tile[128 * 72];                 // [d][s] padded
    const bf16* src = vp + (size_t)bh * S_ * HD_;
    bf16* dst = vt + (size_t)bh * HD_ * S_;

    // read 64 rows x 128 d, scatter-transpose into LDS
    {
        int r = t >> 2;                              // 0..63
        int g = (t & 3) * 4;                         // 4 groups of 8 d per thread
#pragma unroll
        for (int w = 0; w < 4; w++) {
            bf16x8 v8 = *(const bf16x8*)&src[(size_t)(s0 + r) * HD_ + (g + w) * 8];
#pragma unroll
            for (int e = 0; e < 8; e++) tile[((g + w) * 8 + e) * 72 + r] = v8[e];
        }
    }
    __syncthreads();
    // write 128 d-rows x 64 s, coalesced b128
    {
        int d = t >> 1;                              // 0..127
        int sg0 = (t & 1) * 4;
#pragma unroll
        for (int w = 0; w < 4; w++) {
            int sg = sg0 + w;
            *(bf16x8*)&dst[(size_t)d * S_ + s0 + sg * 8] =
                *(const bf16x8*)&tile[d * 72 + sg * 8];
        }
    }
}

// =================== GEMM: C[m,n] = sum_k A[m,k]*W[n,k] ===================
// A planes bf16 via global_load_lds + XOR column swizzle; B f32 VALU-staged.
// MODE 0: split A (xh,xl), sections q|k|v; epilogue *hm, scatter planes (v natural).
// MODE 1: single A (attn_out); epilogue f32.
#define BK 64

template<int MODE>
__global__ __launch_bounds__(256, 3)
void gemm_nt(const bf16* __restrict__ Ah_g, const bf16* __restrict__ Al_g,
             const float* __restrict__ B0, const float* __restrict__ B1,
             const float* __restrict__ B2,
             const float* __restrict__ swp, const float* __restrict__ hm,
             bf16* __restrict__ qh_, bf16* __restrict__ ql_,
             bf16* __restrict__ kh_, bf16* __restrict__ kl_,
             bf16* __restrict__ vp_, float* __restrict__ Cf) {
    const int K = D_;
    __shared__ bf16 Ah[128 * 64];
    __shared__ bf16 Al[128 * 64];
    __shared__ bf16 Bs[128 * 64];
    const int t = threadIdx.x;
    const int wave = t >> 6, lane = t & 63;
    const int wr = wave >> 1, wc = wave & 1;
    const int m0 = blockIdx.y * 128, n0 = blockIdx.x * 128;
    const int lrow = lane & 15, lquad = lane >> 4;
    const float sw = swp[0];

    const int which = (MODE == 0) ? (n0 >> 11) : 0;
    const bool split = (MODE == 0) && (which < 2);

    const float* Bp;
    if (MODE == 0) {
        Bp = (which == 0) ? B0 : ((which == 1) ? B1 : B2);
        Bp += (size_t)(n0 & (D_ - 1)) * K;
    } else {
        Bp = B0 + (size_t)n0 * K;
    }

    const int srow8 = lane >> 3;
    const int sgrp  = lane & 7;
    const int g0 = (lquad)     ^ (lrow & 7);
    const int g1 = (lquad + 4) ^ (lrow & 7);

    f32x4 acc[4][4];
#pragma unroll
    for (int i = 0; i < 4; i++)
#pragma unroll
        for (int j = 0; j < 4; j++) acc[i][j] = (f32x4){0.f, 0.f, 0.f, 0.f};

    for (int k0 = 0; k0 < K; k0 += BK) {
#pragma unroll
        for (int p = 0; p < 4; p++) {
            int r = wave * 32 + p * 8 + srow8;
            int gcol = (sgrp ^ (r & 7)) * 8;
            gld_lds16(Ah_g + (size_t)(m0 + r) * K + k0 + gcol,
                      &Ah[(wave * 32 + p * 8) * 64]);
            if (split)
                gld_lds16(Al_g + (size_t)(m0 + r) * K + k0 + gcol,
                          &Al[(wave * 32 + p * 8) * 64]);
        }
#pragma unroll
        for (int p = 0; p < 4; p++) {
            int r = p * 32 + (t >> 3);
            int gcol = (sgrp ^ (r & 7)) * 8;
            const float* bp = Bp + (size_t)r * K + k0 + gcol;
            float4 blo = *(const float4*)bp;
            float4 bhi = *(const float4*)(bp + 4);
            bf16x8 b8;
            b8[0] = (bf16)(blo.x * sw); b8[1] = (bf16)(blo.y * sw);
            b8[2] = (bf16)(blo.z * sw); b8[3] = (bf16)(blo.w * sw);
            b8[4] = (bf16)(bhi.x * sw); b8[5] = (bf16)(bhi.y * sw);
            b8[6] = (bf16)(bhi.z * sw); b8[7] = (bf16)(bhi.w * sw);
            *(bf16x8*)&Bs[r * 64 + sgrp * 8] = b8;
        }
        __syncthreads();

#pragma unroll
        for (int kk = 0; kk < 2; kk++) {
            const int gA = kk ? g1 : g0;
            bf16x8 afh[4], afl[4], bfr[4];
#pragma unroll
            for (int i = 0; i < 4; i++) {
                int row = wr * 64 + i * 16 + lrow;
                afh[i] = *(const bf16x8*)&Ah[row * 64 + gA * 8];
                if (split) afl[i] = *(const bf16x8*)&Al[row * 64 + gA * 8];
            }
#pragma unroll
            for (int j = 0; j < 4; j++) {
                int row = wc * 64 + j * 16 + lrow;
                bfr[j] = *(const bf16x8*)&Bs[row * 64 + gA * 8];
            }
#pragma unroll
            for (int i = 0; i < 4; i++)
#pragma unroll
                for (int j = 0; j < 4; j++) {
                    acc[i][j] = __builtin_amdgcn_mfma_f32_16x16x32_bf16(
                        afh[i], bfr[j], acc[i][j], 0, 0, 0);
                    if (split)
                        acc[i][j] = __builtin_amdgcn_mfma_f32_16x16x32_bf16(
                            afl[i], bfr[j], acc[i][j], 0, 0, 0);
                }
        }
        __syncthreads();
    }

#pragma unroll
    for (int i = 0; i < 4; i++) {
#pragma unroll
        for (int j = 0; j < 4; j++) {
#pragma unroll
            for (int r = 0; r < 4; r++) {
                int m = m0 + wr * 64 + i * 16 + lquad * 4 + r;
                int n = n0 + wc * 64 + j * 16 + lrow;
                float v = acc[i][j][r];
                if (MODE == 0) {
                    int e = n & (D_ - 1);
                    int h = e >> 7, hd = e & (HD_ - 1);
                    int b = m >> 11, s = m & (S_ - 1);
                    v *= hm[h];
                    size_t idx = (((size_t)b * H_ + h) * S_ + s) * HD_ + hd;
                    if (which == 2) {
                        vp_[idx] = (bf16)v;          // natural layout (coalesced)
                    } else {
                        bf16 hv = (bf16)v;
                        bf16 lv = (bf16)(v - (float)hv);
                        if (which == 0) { qh_[idx] = hv; ql_[idx] = lv; }
                        else            { kh_[idx] = hv; kl_[idx] = lv; }
                    }
                } else {
                    Cf[(size_t)m * D_ + n] = v;
                }
            }
        }
    }
}

// =================== causal flash attention (MFMA, split QK) ===================
// R5 structure (1024 blocks, 64 q-rows, wave = 16 rows, reversed qblk), but all
// LDS staging (K hi/lo + V^T) via global_load_lds with XOR source swizzle:
// zero staging VALU, no pads. LDS 57 KiB -> 2 blocks/CU.
#define SPLD 72

__global__ __launch_bounds__(256, 2)
void attn_kernel(const bf16* __restrict__ qh_, const bf16* __restrict__ ql_,
                 const bf16* __restrict__ kh_, const bf16* __restrict__ kl_,
                 const bf16* __restrict__ vt_, const float* __restrict__ am,
                 bf16* __restrict__ outp) {
    const int bh = blockIdx.x & 31;
    const int qblk = 31 - (blockIdx.x >> 5);
    const int b = bh >> 4, h = bh & 15;
    const int i0 = qblk * 64;
    const int t = threadIdx.x, wave = t >> 6, lane = t & 63;
    const int lrow = lane & 15, quad = lane >> 4;

    __shared__ bf16 skh[64 * 128];                 // swizzled [j][d]
    __shared__ bf16 skl[64 * 128];
    __shared__ bf16 svt[128 * 64];                 // swizzled [d][j]
    __shared__ bf16 sp[4][16 * SPLD];              // per-wave P strip (padded)

    const size_t kbase = (size_t)bh * S_ * HD_;
    const size_t vbase = (size_t)bh * HD_ * S_;

    // Q fragments (hi+lo) straight to registers
    const int qrow = i0 + wave * 16 + lrow;
    bf16x8 qhf[4], qlf[4];
#pragma unroll
    for (int c = 0; c < 4; c++) {
        qhf[c] = *(const bf16x8*)&qh_[kbase + (size_t)qrow * HD_ + c * 32 + quad * 8];
        qlf[c] = *(const bf16x8*)&ql_[kbase + (size_t)qrow * HD_ + c * 32 + quad * 8];
    }

    float m_i[4], l_i[4];
    f32x4 O[8];
#pragma unroll
    for (int r = 0; r < 4; r++) { m_i[r] = -INFINITY; l_i[r] = 0.f; }
#pragma unroll
    for (int n2 = 0; n2 < 8; n2++) O[n2] = (f32x4){0.f, 0.f, 0.f, 0.f};

    const float scale = 0.08838834764831845f;  // 1/sqrt(128)

    for (int j0 = 0; j0 <= i0; j0 += 64) {
        __syncthreads();
        // K chunk hi/lo: async staged, XOR swizzle on source column.
        // wave stages rows [wave*16, wave*16+16), 4 rows per issue.
#pragma unroll
        for (int p = 0; p < 4; p++) {
            int rb = wave * 16 + p * 4;
            int r = rb + (lane >> 4);
            int gl = ((lane & 15) ^ (r & 7)) * 8;
            gld_lds16(kh_ + kbase + (size_t)(j0 + r) * HD_ + gl, &skh[rb * 128]);
            gld_lds16(kl_ + kbase + (size_t)(j0 + r) * HD_ + gl, &skl[rb * 128]);
        }
        // V^T chunk: async staged from global V^T, 8 rows per issue.
#pragma unroll
        for (int p = 0; p < 4; p++) {
            int db = wave * 32 + p * 8;
            int d = db + (lane >> 3);
            int gl = ((lane & 7) ^ (d & 7)) * 8;
            gld_lds16(vt_ + vbase + (size_t)d * S_ + j0 + gl, &svt[db * 64]);
        }
        __syncthreads();

        float amadd[4];
#pragma unroll
        for (int nt = 0; nt < 4; nt++)
            amadd[nt] = (1.0f - am[b * S_ + j0 + nt * 16 + lrow]) * -10000.0f;

        // QK^T: 16 rows x 64 cols, split 3-MFMA, swizzled B-frag reads
        f32x4 s4[4];
#pragma unroll
        for (int nt = 0; nt < 4; nt++) s4[nt] = (f32x4){0.f, 0.f, 0.f, 0.f};
#pragma unroll
        for (int c = 0; c < 4; c++) {
#pragma unroll
            for (int nt = 0; nt < 4; nt++) {
                int ka = (nt * 16 + lrow) * 128 + (((c * 4 + quad) ^ (lrow & 7)) * 8);
                bf16x8 kb8 = *(const bf16x8*)&skh[ka];
                bf16x8 lb8 = *(const bf16x8*)&skl[ka];
                s4[nt] = __builtin_amdgcn_mfma_f32_16x16x32_bf16(qhf[c], kb8, s4[nt], 0, 0, 0);
                s4[nt] = __builtin_amdgcn_mfma_f32_16x16x32_bf16(qhf[c], lb8, s4[nt], 0, 0, 0);
                s4[nt] = __builtin_amdgcn_mfma_f32_16x16x32_bf16(qlf[c], kb8, s4[nt], 0, 0, 0);
            }
        }

        const bool diag = (j0 == i0);
#pragma unroll
        for (int r = 0; r < 4; r++) {
            const int rrow = wave * 16 + quad * 4 + r;
            float sv[4], pw[4];
            float mx = -INFINITY;
#pragma unroll
            for (int nt = 0; nt < 4; nt++) {
                float xv = s4[nt][r] * scale + amadd[nt];
                if (diag && (nt * 16 + lrow) > rrow) xv = -INFINITY;
                sv[nt] = xv;
                mx = fmaxf(mx, xv);
            }
#pragma unroll
            for (int off = 1; off < 16; off <<= 1) mx = fmaxf(mx, __shfl_xor(mx, off));
            float mnew = fmaxf(m_i[r], mx);
            float alpha = __expf(m_i[r] - mnew);
            float ps = 0.f;
#pragma unroll
            for (int nt = 0; nt < 4; nt++) { pw[nt] = __expf(sv[nt] - mnew); ps += pw[nt]; }
#pragma unroll
            for (int off = 1; off < 16; off <<= 1) ps += __shfl_xor(ps, off);
            l_i[r] = l_i[r] * alpha + ps;
            m_i[r] = mnew;
#pragma unroll
            for (int n2 = 0; n2 < 8; n2++) O[n2][r] *= alpha;
#pragma unroll
            for (int nt = 0; nt < 4; nt++)
                sp[wave][(quad * 4 + r) * SPLD + nt * 16 + lrow] = (bf16)pw[nt];
        }
        __asm__ volatile("s_waitcnt lgkmcnt(0)" ::: "memory");   // sp per-wave

        // PV: O += P * V, swizzled V^T frag reads
#pragma unroll
        for (int k2 = 0; k2 < 2; k2++) {
            bf16x8 pf = *(const bf16x8*)&sp[wave][lrow * SPLD + k2 * 32 + quad * 8];
            const int gp = ((quad + k2 * 4) ^ (lrow & 7)) * 8;
#pragma unroll
            for (int n2 = 0; n2 < 8; n2++) {
                bf16x8 vf8 = *(const bf16x8*)&svt[(n2 * 16 + lrow) * 64 + gp];
                O[n2] = __builtin_amdgcn_mfma_f32_16x16x32_bf16(pf, vf8, O[n2], 0, 0, 0);
            }
        }
    }

    float inv[4];
#pragma unroll
    for (int r = 0; r < 4; r++) inv[r] = 1.0f / l_i[r];
#pragma unroll
    for (int n2 = 0; n2 < 8; n2++)
#pragma unroll
        for (int r = 0; r < 4; r++) {
            int srow = i0 + wave * 16 + quad * 4 + r;
            outp[((size_t)(b * S_ + srow)) * D_ + h * HD_ + n2 * 16 + lrow] =
                (bf16)(O[n2][r] * inv[r]);
        }
}

// =================== launch ===================
extern "C" void kernel_launch(void* const* d_in, const int* in_sizes, int n_in,
                              void* d_out, int out_size, void* d_ws, size_t ws_size,
                              hipStream_t stream) {
    const float* x  = (const float*)d_in[0];
    const float* qm = (const float*)d_in[1];
    const float* km = (const float*)d_in[2];
    const float* vm = (const float*)d_in[3];
    const float* om = (const float*)d_in[4];
    const float* hm = (const float*)d_in[5];
    const float* am = (const float*)d_in[6];
    const float* sw = (const float*)d_in[7];
    float* out = (float*)d_out;

    // ws (96 MiB): [xh | xl | qh | ql | kh | kl]. d_out (32 MiB) doubles as
    // scratch: vp (natural) at +0, vt (transposed) at +16M — both dead before
    // gemm1 writes out. attn_out overlays xh/xl after gemm0.
    const size_t P = (size_t)B_ * H_ * S_ * HD_ * sizeof(bf16);   // 16777216
    char* ws = (char*)d_ws;
    bf16* xh = (bf16*)(ws + 0 * P);
    bf16* xl = (bf16*)(ws + 1 * P);
    bf16* qh = (bf16*)(ws + 2 * P);
    bf16* ql = (bf16*)(ws + 3 * P);
    bf16* kh = (bf16*)(ws + 4 * P);
    bf16* kl = (bf16*)(ws + 5 * P);
    bf16* vp = (bf16*)d_out;                    // [bh][s][d]
    bf16* vt = (bf16*)((char*)d_out + P);       // [bh][d][s]
    bf16* attn_out = (bf16*)(ws + 0 * P);

    precast_kernel<<<(B_ * S_ * D_) / (256 * 8), 256, 0, stream>>>(x, xh, xl);

    // QKV projection, split-precision q,k: M=4096, N=6144, K=2048
    gemm_nt<0><<<dim3(48, 32), 256, 0, stream>>>(
        xh, xl, qm, km, vm, sw, hm, qh, ql, kh, kl, vp, nullptr);

    // V transpose (one-off): [bh][s][d] -> [bh][d][s]
    transpose_v<<<1024, 256, 0, stream>>>(vp, vt);

    // attention: 1024 blocks (32 qblk x 32 bh), reversed qblk for backfill
    attn_kernel<<<1024, 256, 0, stream>>>(qh, ql, kh, kl, vt, am, attn_out);

    // output projection: M=4096, N=2048, K=2048, f32 out
    gemm_nt<1><<<dim3(16, 32), 256, 0, stream>>>(
        attn_out, nullptr, om, nullptr, nullptr, sw, hm,
        nullptr, nullptr, nullptr, nullptr, nullptr, out);
}